// Round 1
// baseline (634.076 us; speedup 1.0000x reference)
//
#include <hip/hip_runtime.h>

#define T_DATA 200000
#define E_NO 400
#define I_NO 100
#define SUB_NO 20
#define N_BASIS 20
#define T_NO 200

typedef unsigned short u16;
typedef unsigned int u32;
typedef unsigned long long u64;

// ---- workspace layout (ws_size ~1.28 GB; we use ~33.7 MB) ----
#define WS_K4    0                       // 4000 float4 = 64000
#define WS_HIST2 64000                   // 200 float2
#define WS_MASKS 65600                   // 240 u64 = 1920 B (E: 20x8, I: 20x4)
#define WS_SYNE  131072                  // 20*200000 u16 = 8e6
#define WS_SYNI  (WS_SYNE + 8000000)
#define WS_SNS   (WS_SYNI + 8000000)
#define WS_SS    (WS_SNS + 8000000)
#define WS_HF    (WS_SS + 8000000)       // 200000 float2 = 1.6e6

__device__ __forceinline__ u16 f2bf(float f) {
    union { float f; u32 u; } v; v.f = f;
    u32 u = v.u;
    u32 lsb = (u >> 16) & 1u;
    u += 0x7fffu + lsb;            // RNE
    return (u16)(u >> 16);
}
__device__ __forceinline__ float bf2f(u16 b) {
    union { u32 u; float f; } v; v.u = ((u32)b) << 16; return v.f;
}
__device__ __forceinline__ void unpack8(uint4 u, float* x) {
    union { u32 u; float f; } c;
    c.u = u.x << 16;          x[0] = c.f;
    c.u = u.x & 0xffff0000u;  x[1] = c.f;
    c.u = u.y << 16;          x[2] = c.f;
    c.u = u.y & 0xffff0000u;  x[3] = c.f;
    c.u = u.z << 16;          x[4] = c.f;
    c.u = u.z & 0xffff0000u;  x[5] = c.f;
    c.u = u.w << 16;          x[6] = c.f;
    c.u = u.w & 0xffff0000u;  x[7] = c.f;
}
__device__ __forceinline__ float fast_tanh(float x) {
    x = fminf(fmaxf(x, -15.f), 15.f);
    float e = __expf(2.f * x);
    return 1.f - 2.f / (e + 1.f);
}
__device__ __forceinline__ float fast_sigmoid(float x) {
    x = fminf(fmaxf(x, -30.f), 30.f);
    return 1.f / (1.f + __expf(-x));
}

// ============================================================================
// k_setup: 22 blocks. 0..19 subunit filters -> k4/outF; 20 hist kernels;
// 21 per-subunit spike bitmasks (ballot bit order: col j -> chunk=j>>8,
// lane=(j&255)>>2, comp=j&3 for E; lane=j>>2, comp=j&3 for I).
// ============================================================================
__global__ __launch_bounds__(256) void k_setup(
    const float* __restrict__ Wns, const float* __restrict__ Tau,
    const float* __restrict__ Del, const float* __restrict__ Wsyns,
    const float* __restrict__ HwS, const float* __restrict__ HwNS,
    const float* __restrict__ Cse, const float* __restrict__ Csi,
    float4* __restrict__ k4, float2* __restrict__ hist2,
    u32* __restrict__ masks32, float* __restrict__ outF)
{
    __shared__ float cb[N_BASIS * T_NO];
    __shared__ u32 m32[480];             // 240 u64: E 20x8, then I 20x4
    const int tid = threadIdx.x;
    const int b = blockIdx.x;
    const float PI = 3.14159265358979323846f;

    if (b == 21) {
        for (int k = tid; k < 480; k += 256) m32[k] = 0;
        __syncthreads();
        for (int j = tid; j < E_NO; j += 256) {
            int a = 0;
            for (int s = 0; s < SUB_NO; ++s)
                if (Cse[s * E_NO + j] > 0.5f) a = s;
            int ch = j >> 8, r = j & 255, ln = r >> 2, cp = r & 3;
            int widx = (a * 8 + ch * 4 + cp) * 2 + (ln >> 5);
            atomicOr(&m32[widx], 1u << (ln & 31));
        }
        for (int j = tid; j < I_NO; j += 256) {
            int a = 0;
            for (int s = 0; s < SUB_NO; ++s)
                if (Csi[s * I_NO + j] > 0.5f) a = s;
            int ln = j >> 2, cp = j & 3;
            int widx = 320 + (a * 4 + cp) * 2 + (ln >> 5);
            atomicOr(&m32[widx], 1u << (ln & 31));
        }
        __syncthreads();
        for (int k = tid; k < 480; k += 256) masks32[k] = m32[k];
        return;
    }

    for (int it = tid; it < N_BASIS * T_NO; it += 256) {
        int bb = it / T_NO, j = it - bb * T_NO;
        float phi = 1.57079632679489662f * (float)bb;
        float raw = 5.0f * logf((float)j + 1.0f);
        float v = 0.f;
        if (raw >= phi - PI && raw <= phi + PI) v = 0.5f * cosf(raw - phi) + 0.5f;
        cb[it] = v;
    }
    __syncthreads();

    if (b < 20) {
        const int s = b;
        if (tid < T_NO) {
            const int j = tid;
            float tau_e = Tau[s * 2 + 0]; tau_e *= tau_e;
            float tau_i = Tau[s * 2 + 1]; tau_i *= tau_i;
            float de = Del[s * 2 + 0], di = Del[s * 2 + 1];
            float we = Wns[s * 2 + 0]; we *= we;
            float wi = Wns[s * 2 + 1]; wi *= wi;
            float te = fmaxf((float)j - de, 0.f) / tau_e;
            float ti = fmaxf((float)j - di, 0.f) / tau_i;
            float eNs = te * expf(-te) * we;
            float iNs = -ti * expf(-ti) * wi;
            float eS = 0.f, iS = 0.f;
            for (int bb = 0; bb < N_BASIS; ++bb) {
                float w0 = Wsyns[(s * N_BASIS + bb) * 2 + 0];
                float w1 = Wsyns[(s * N_BASIS + bb) * 2 + 1];
                float c = cb[bb * T_NO + j];
                eS += w0 * w0 * c;
                iS -= w1 * w1 * c;
            }
            int it = s * T_NO + j;
            k4[it] = make_float4(eNs, iNs, eS, iS);
            outF[it]         = eNs;
            outF[4000 + it]  = iNs;
            outF[8000 + it]  = eS;
            outF[12000 + it] = iS;
        }
    } else {
        if (tid < T_NO) {
            const int j = tid;
            float hn = 0.f, hs = 0.f;
            for (int bb = 0; bb < N_BASIS; ++bb) {
                float c = cb[bb * T_NO + j];
                hn += HwNS[bb] * c;
                hs += HwS[bb] * c;
            }
            hist2[j] = make_float2(hn, hs);
            outF[16000 + j] = hn;
            outF[16200 + j] = hs;
        }
    }
}

// ============================================================================
// k_spikes (ballot+popcount rewrite): syn = S @ C^T is a segment-sum of 0/1
// spikes = popcount(ballot & subunit_mask). Lanes = columns (coalesced float4
// loads), ballot masks are wave-uniform SGPRs; lanes 0..19 hold per-E-subunit
// masks, lanes 20..39 per-I-subunit masks. ~104 LDS ops per wave per 64 t
// (vs ~32000 in the gather version). Wave-autonomous, no __syncthreads.
// ============================================================================
__global__ __launch_bounds__(256) void k_spikes(
    const float* __restrict__ Se, const float* __restrict__ Si,
    const u64* __restrict__ masks,
    u16* __restrict__ synEb, u16* __restrict__ synIb)
{
    __shared__ u16 tile[4][40 * 66];     // per wave [40 rows][64 t], stride 66
    const int tid = threadIdx.x;
    const int wv = tid >> 6, lane = tid & 63;
    const int t0 = (blockIdx.x * 4 + wv) * 64;
    if (t0 >= T_DATA) return;

    u64 me0 = 0, me1 = 0, me2 = 0, me3 = 0, me4 = 0, me5 = 0, me6 = 0, me7 = 0;
    u64 mi0 = 0, mi1 = 0, mi2 = 0, mi3 = 0;
    if (lane < 20) {
        const u64* mp = masks + lane * 8;
        me0 = mp[0]; me1 = mp[1]; me2 = mp[2]; me3 = mp[3];
        me4 = mp[4]; me5 = mp[5]; me6 = mp[6]; me7 = mp[7];
    } else if (lane < 40) {
        const u64* mp = masks + 160 + (lane - 20) * 4;
        mi0 = mp[0]; mi1 = mp[1]; mi2 = mp[2]; mi3 = mp[3];
    }
    u16* tw = tile[wv];

#pragma unroll 2
    for (int tt = 0; tt < 64; ++tt) {
        const int t = t0 + tt;
        const float4* rE = (const float4*)(Se + (size_t)t * E_NO);
        const float4* rI = (const float4*)(Si + (size_t)t * I_NO);
        float4 e0 = rE[lane];                                   // cols 0..255
        float4 e1 = make_float4(0.f, 0.f, 0.f, 0.f);            // cols 256..399
        if (lane < 36) e1 = rE[64 + lane];
        float4 i0 = make_float4(0.f, 0.f, 0.f, 0.f);            // cols 0..99
        if (lane < 25) i0 = rI[lane];
        u64 b0 = __ballot(e0.x != 0.f);
        u64 b1 = __ballot(e0.y != 0.f);
        u64 b2 = __ballot(e0.z != 0.f);
        u64 b3 = __ballot(e0.w != 0.f);
        u64 b4 = __ballot(e1.x != 0.f);
        u64 b5 = __ballot(e1.y != 0.f);
        u64 b6 = __ballot(e1.z != 0.f);
        u64 b7 = __ballot(e1.w != 0.f);
        u64 c0 = __ballot(i0.x != 0.f);
        u64 c1 = __ballot(i0.y != 0.f);
        u64 c2 = __ballot(i0.z != 0.f);
        u64 c3 = __ballot(i0.w != 0.f);
        if (lane < 20) {
            int c = __popcll(b0 & me0) + __popcll(b1 & me1)
                  + __popcll(b2 & me2) + __popcll(b3 & me3)
                  + __popcll(b4 & me4) + __popcll(b5 & me5)
                  + __popcll(b6 & me6) + __popcll(b7 & me7);
            tw[lane * 66 + tt] = (u16)c;
        } else if (lane < 40) {
            int c = __popcll(c0 & mi0) + __popcll(c1 & mi1)
                  + __popcll(c2 & mi2) + __popcll(c3 & mi3);
            tw[lane * 66 + tt] = (u16)c;
        }
    }
    // intra-wave cross-lane LDS visibility (no block barrier needed)
    asm volatile("s_waitcnt lgkmcnt(0)" ::: "memory");

    // writeout: 40 rows x 64 t, counts are exact small ints -> bf16 exact
#pragma unroll 4
    for (int s = 0; s < 40; ++s) {
        float f = (float)tw[s * 66 + lane];
        u16 b = f2bf(f);
        if (s < 20) synEb[(size_t)s * T_DATA + t0 + lane] = b;
        else        synIb[(size_t)(s - 20) * T_DATA + t0 + lane] = b;
    }
}

// ============================================================================
// k_conv (R10-proven): depthwise conv. blockIdx.y 0..4 = 4 subunits each;
// 5 = hist-of-Z (hist[t] = conv(Z)[t-1] -> hfilt f32). 24 KB LDS -> 6/CU.
// ============================================================================
#define TT 512
#define WROW 712
__global__ __launch_bounds__(256) void k_conv(
    const u16* __restrict__ synEb, const u16* __restrict__ synIb,
    const float* __restrict__ Z,
    const float4* __restrict__ k4g, const float2* __restrict__ hist2g,
    u16* __restrict__ synNSb, u16* __restrict__ synSb,
    float2* __restrict__ hfilt)
{
    __shared__ __align__(16) u16 wE[4 * WROW];
    __shared__ __align__(16) u16 wI[4 * WROW];
    __shared__ __align__(16) float4 k4l[4 * T_NO];
    const int tid = threadIdx.x;
    const int t0 = blockIdx.x * TT;
    const int g  = blockIdx.y;
    const int W0 = t0 - 200;

    if (g < 5) {
        for (int q = tid; q < 712; q += 256) {
            int arr = (q >= 356) ? 1 : 0;
            int qq = q - arr * 356;
            int row = qq / 89, c = qq - row * 89;
            int s = g * 4 + row;
            const u16* src = (arr ? synIb : synEb) + (size_t)s * T_DATA;
            u16* dst = (arr ? wI : wE) + row * WROW + c * 8;
            int gg = W0 + c * 8;
            if (gg >= 0 && gg + 8 <= T_DATA) {
                *(uint4*)dst = *(const uint4*)(src + gg);
            } else {
                for (int e = 0; e < 8; ++e) {
                    int t = gg + e;
                    dst[e] = (t >= 0 && t < T_DATA) ? src[t] : (u16)0;
                }
            }
        }
        for (int q = tid; q < 800; q += 256) {
            int su = q / 200, j = q - su * 200;
            k4l[q] = k4g[(g * 4 + su) * T_NO + j];
        }
    } else {
        for (int q = tid; q < 623; q += 256) {
            if (q < 356) ((uint4*)wI)[q] = make_uint4(0, 0, 0, 0);
            else         ((uint4*)wE)[q - 356 + 89] = make_uint4(0, 0, 0, 0);
        }
        for (int c = tid; c < 89; c += 256) {
            int gg = W0 + c * 8;
            u16 zb[8];
            for (int e = 0; e < 8; ++e) {
                int t = gg + e;
                zb[e] = (t >= 0 && t < T_DATA) ? f2bf(Z[t]) : (u16)0;
            }
            u32 w0 = (u32)zb[0] | ((u32)zb[1] << 16);
            u32 w1 = (u32)zb[2] | ((u32)zb[3] << 16);
            u32 w2 = (u32)zb[4] | ((u32)zb[5] << 16);
            u32 w3 = (u32)zb[6] | ((u32)zb[7] << 16);
            *(uint4*)(wE + c * 8) = make_uint4(w0, w1, w2, w3);
        }
        for (int q = tid; q < 800; q += 256) {
            int su = q / 200, j = q - su * 200;
            float4 v = make_float4(0.f, 0.f, 0.f, 0.f);
            if (su == 0) {
                float2 h = hist2g[j];
                v = make_float4(h.x, 0.f, h.y, 0.f);
            }
            k4l[q] = v;
        }
    }
    __syncthreads();

    const int wv = tid >> 6;
    const int slot = tid & 63;
    const int bT = slot * 8;
    const u16* rowE = wE + wv * WROW;
    const u16* rowI = wI + wv * WROW;

    float aN[8], aS2[8];
#pragma unroll
    for (int m = 0; m < 8; ++m) { aN[m] = 0.f; aS2[m] = 0.f; }

#pragma unroll 1
    for (int jj = 0; jj <= 192; jj += 8) {
        const int p = bT + 192 - jj;
        float xe[16], xi[16];
        uint4 eA = *(const uint4*)(rowE + p);
        uint4 eB = *(const uint4*)(rowE + p + 8);
        uint4 iA = *(const uint4*)(rowI + p);
        uint4 iB = *(const uint4*)(rowI + p + 8);
        unpack8(eA, xe); unpack8(eB, xe + 8);
        unpack8(iA, xi); unpack8(iB, xi + 8);
#pragma unroll
        for (int k = 0; k < 8; ++k) {
            float4 kk = k4l[wv * T_NO + jj + k];
#pragma unroll
            for (int m = 0; m < 8; ++m) {
                float e = xe[m + 8 - k];
                float ii = xi[m + 8 - k];
                aN[m]  = fmaf(e, kk.x, fmaf(ii, kk.y, aN[m]));
                aS2[m] = fmaf(e, kk.z, fmaf(ii, kk.w, aS2[m]));
            }
        }
    }

    if (g < 5) {
        const int s = g * 4 + wv;
        const int t = t0 + bT;
        u32 w0 = (u32)f2bf(aN[0]) | ((u32)f2bf(aN[1]) << 16);
        u32 w1 = (u32)f2bf(aN[2]) | ((u32)f2bf(aN[3]) << 16);
        u32 w2 = (u32)f2bf(aN[4]) | ((u32)f2bf(aN[5]) << 16);
        u32 w3 = (u32)f2bf(aN[6]) | ((u32)f2bf(aN[7]) << 16);
        u32 v0 = (u32)f2bf(aS2[0]) | ((u32)f2bf(aS2[1]) << 16);
        u32 v1 = (u32)f2bf(aS2[2]) | ((u32)f2bf(aS2[3]) << 16);
        u32 v2 = (u32)f2bf(aS2[4]) | ((u32)f2bf(aS2[5]) << 16);
        u32 v3 = (u32)f2bf(aS2[6]) | ((u32)f2bf(aS2[7]) << 16);
        if (t + 8 <= T_DATA) {
            *(uint4*)(synNSb + (size_t)s * T_DATA + t) = make_uint4(w0, w1, w2, w3);
            *(uint4*)(synSb  + (size_t)s * T_DATA + t) = make_uint4(v0, v1, v2, v3);
        } else if (t < T_DATA) {
            for (int m = 0; m < 8 && t + m < T_DATA; ++m) {
                synNSb[(size_t)s * T_DATA + t + m] = f2bf(aN[m]);
                synSb[(size_t)s * T_DATA + t + m] = f2bf(aS2[m]);
            }
        }
    } else if (wv == 0) {
#pragma unroll
        for (int m = 0; m < 8; ++m) {
            int tt = t0 + bT + m + 1;
            if (tt < T_DATA) hfilt[tt] = make_float2(aN[m], aS2[m]);
        }
        if (blockIdx.x == 0 && tid == 0) hfilt[0] = make_float2(0.f, 0.f);
    }
}

// ============================================================================
// k_tree (R10-proven): tree recursion + f32 outputs (hist precomputed).
// ============================================================================
#define CT 256
__global__ __launch_bounds__(256) void k_tree(
    const u16* __restrict__ synNSb, const u16* __restrict__ synSb,
    const float2* __restrict__ hfilt,
    const int* __restrict__ Cden,
    const float* __restrict__ WsubNS, const float* __restrict__ WsubS,
    const float* __restrict__ Vo, const float* __restrict__ ThNS,
    const float* __restrict__ ThS,
    float* __restrict__ outV, float* __restrict__ outZ)
{
    __shared__ __align__(16) u16 lNS[SUB_NO * CT];
    __shared__ __align__(16) u16 lS[SUB_NO * CT];
    __shared__ float AS[SUB_NO][SUB_NO], AN[SUB_NO][SUB_NO];
    __shared__ float ths[SUB_NO], thn[SUB_NO];
    __shared__ float wn20s, vos;
    const int tid = threadIdx.x;
    const int t0 = blockIdx.x * CT;

    for (int q = tid; q < 1280; q += 256) {
        int arr = (q >= 640) ? 1 : 0;
        int qq = q - arr * 640;
        int row = qq >> 5, c = qq & 31;
        const u16* src = (arr ? synSb : synNSb) + (size_t)row * T_DATA;
        u16* dst = (arr ? lS : lNS) + row * CT + c * 8;
        int gg = t0 + c * 8;
        if (gg + 8 <= T_DATA) {
            *(uint4*)dst = *(const uint4*)(src + gg);
        } else {
            for (int e = 0; e < 8; ++e) {
                int t = gg + e;
                dst[e] = (t < T_DATA) ? src[t] : (u16)0;
            }
        }
    }
    for (int k = tid; k < SUB_NO * SUB_NO; k += 256) {
        int idx = k / SUB_NO, c = k - idx * SUB_NO;
        float m = (float)Cden[k];
        float wsv = WsubS[c];
        float wnv = WsubNS[c];
        AS[idx][c] = m * wsv * wsv;
        AN[idx][c] = m * wnv * wnv;
    }
    if (tid < SUB_NO) { ths[tid] = ThS[tid]; thn[tid] = ThNS[tid]; }
    if (tid == 0) {
        float w = WsubNS[0];
        wn20s = w * w;
        vos = Vo[0];
    }
    __syncthreads();

    const int t = t0 + tid;
    float2 hf = make_float2(0.f, 0.f);
    if (t < T_DATA) hf = hfilt[t];

    float vs[SUB_NO], vn[SUB_NO];
#pragma unroll
    for (int c = 0; c < SUB_NO; ++c) { vs[c] = 0.f; vn[c] = 0.f; }
#pragma unroll
    for (int idx = SUB_NO - 1; idx >= 1; --idx) {
        float cs = 0.f, cn = 0.f;
#pragma unroll
        for (int c = 0; c < SUB_NO; ++c) {
            cs = fmaf(AS[idx][c], vs[c], cs);
            cn = fmaf(AN[idx][c], vn[c], cn);
        }
        float synS_v = bf2f(lS[idx * CT + tid]);
        float synN_v = bf2f(lNS[idx * CT + tid]);
        vs[idx] = fast_tanh(synS_v + cs + ths[idx]);
        vn[idx] = fast_tanh(synN_v + cn + thn[idx]);
    }
    float cs0 = 0.f, cn0 = 0.f;
#pragma unroll
    for (int c = 0; c < SUB_NO; ++c) {
        cs0 = fmaf(AS[0][c], vs[c], cs0);
        cn0 = fmaf(AN[0][c], vn[c], cn0);
    }
    float s0  = fast_sigmoid(hf.y + bf2f(lS[tid]) + cs0 + ths[0]);
    float ns0 = fast_tanh(hf.x + bf2f(lNS[tid]) + cn0 + thn[0]);

    if (t < T_DATA) {
        outV[t] = ns0 * wn20s + vos;
        outZ[t] = s0;
    }
}

// ============================================================================
extern "C" void kernel_launch(void* const* d_in, const int* in_sizes, int n_in,
                              void* d_out, int out_size, void* d_ws, size_t ws_size,
                              hipStream_t stream)
{
    const float* Se    = (const float*)d_in[0];
    const float* Si    = (const float*)d_in[1];
    const float* Z     = (const float*)d_in[2];
    const int*   Cden  = (const int*)d_in[3];
    const float* Cse   = (const float*)d_in[4];
    const float* Csi   = (const float*)d_in[5];
    const float* Wns   = (const float*)d_in[6];
    const float* Tau   = (const float*)d_in[7];
    const float* Del   = (const float*)d_in[8];
    const float* Wsyns = (const float*)d_in[9];
    const float* WsubNS= (const float*)d_in[10];
    const float* WsubS = (const float*)d_in[11];
    const float* Vo    = (const float*)d_in[12];
    const float* ThNS  = (const float*)d_in[13];
    const float* ThS   = (const float*)d_in[14];
    const float* HwS   = (const float*)d_in[15];
    const float* HwNS  = (const float*)d_in[16];

    char* ws = (char*)d_ws;
    float4* k4    = (float4*)(ws + WS_K4);
    float2* hist2 = (float2*)(ws + WS_HIST2);
    u64*    masks = (u64*)(ws + WS_MASKS);
    u16*    synEb = (u16*)(ws + WS_SYNE);
    u16*    synIb = (u16*)(ws + WS_SYNI);
    u16*    synNSb= (u16*)(ws + WS_SNS);
    u16*    synSb = (u16*)(ws + WS_SS);
    float2* hfilt = (float2*)(ws + WS_HF);

    float* outV = (float*)d_out;
    float* outZ = outV + T_DATA;
    float* outF = outV + 2 * T_DATA;

    k_setup<<<22, 256, 0, stream>>>(Wns, Tau, Del, Wsyns, HwS, HwNS, Cse, Csi,
                                    k4, hist2, (u32*)masks, outF);
    // 3125 waves of 64 timesteps each, 4 waves/block
    k_spikes<<<(3125 + 3) / 4, 256, 0, stream>>>(Se, Si, masks, synEb, synIb);
    dim3 gc((T_DATA + TT - 1) / TT, 6);
    k_conv<<<gc, 256, 0, stream>>>(synEb, synIb, Z, k4, hist2,
                                   synNSb, synSb, hfilt);
    k_tree<<<(T_DATA + CT - 1) / CT, 256, 0, stream>>>(
        synNSb, synSb, hfilt, Cden, WsubNS, WsubS, Vo, ThNS, ThS,
        outV, outZ);
}

// Round 2
// 604.949 us; speedup vs baseline: 1.0481x; 1.0481x over previous
//
#include <hip/hip_runtime.h>

#define T_DATA 200000
#define E_NO 400
#define I_NO 100
#define SUB_NO 20
#define N_BASIS 20
#define T_NO 200

typedef unsigned short u16;
typedef unsigned int u32;
typedef unsigned long long u64;
typedef _Float16 hf;
typedef _Float16 half2_t __attribute__((ext_vector_type(2)));

// ---- workspace layout (ws ~1.28 GB; we use ~33.7 MB) ----
#define WS_KT    0                        // 21*200 uint2 = 33600 (reversed f16 tap pairs)
#define WS_MASKS 33600                    // 240 u64 = 1920
#define WS_SYNEI 65536                    // 20*200000 u32 (e,i) f16 pairs = 16e6
#define WS_SNS   (WS_SYNEI + 16000000)    // 20*200000 u16 f16
#define WS_SS    (WS_SNS + 8000000)
#define WS_HF    (WS_SS + 8000000)        // 200000 float2

__device__ __forceinline__ u16 f2h(float f) {
    hf h = (hf)f; u16 b; __builtin_memcpy(&b, &h, 2); return b;
}
__device__ __forceinline__ float h2f(u16 b) {
    hf h; __builtin_memcpy(&h, &b, 2); return (float)h;
}
__device__ __forceinline__ float dot2(u32 a, u32 b, float c) {
    half2_t ha, hb;
    __builtin_memcpy(&ha, &a, 4);
    __builtin_memcpy(&hb, &b, 4);
    return __builtin_amdgcn_fdot2(ha, hb, c, false);
}
__device__ __forceinline__ float fast_tanh(float x) {
    x = fminf(fmaxf(x, -15.f), 15.f);
    float e = __expf(2.f * x);
    return 1.f - 2.f / (e + 1.f);
}
__device__ __forceinline__ float fast_sigmoid(float x) {
    x = fminf(fmaxf(x, -30.f), 30.f);
    return 1.f / (1.f + __expf(-x));
}

// ============================================================================
// k_setup: 22 blocks. 0..19 per-subunit taps -> ktap (REVERSED, f16 (e,i)
// pairs) + outF f32; 20 hist taps; 21 per-subunit ballot bitmasks.
// ktap[su*200+u] = { pack(kE_N[199-u], kI_N[199-u]), pack(kE_S[199-u], kI_S[199-u]) }
// su=20: { pack(hn[199-u], 0), pack(hs[199-u], 0) }
// ============================================================================
__global__ __launch_bounds__(256) void k_setup(
    const float* __restrict__ Wns, const float* __restrict__ Tau,
    const float* __restrict__ Del, const float* __restrict__ Wsyns,
    const float* __restrict__ HwS, const float* __restrict__ HwNS,
    const float* __restrict__ Cse, const float* __restrict__ Csi,
    uint2* __restrict__ ktap, u32* __restrict__ masks32,
    float* __restrict__ outF)
{
    __shared__ float cb[N_BASIS * T_NO];
    __shared__ u32 m32[480];             // 240 u64: E 20x8, then I 20x4
    const int tid = threadIdx.x;
    const int b = blockIdx.x;
    const float PI = 3.14159265358979323846f;

    if (b == 21) {
        for (int k = tid; k < 480; k += 256) m32[k] = 0;
        __syncthreads();
        for (int j = tid; j < E_NO; j += 256) {
            int a = 0;
            for (int s = 0; s < SUB_NO; ++s)
                if (Cse[s * E_NO + j] > 0.5f) a = s;
            int ch = j >> 8, r = j & 255, ln = r >> 2, cp = r & 3;
            int widx = (a * 8 + ch * 4 + cp) * 2 + (ln >> 5);
            atomicOr(&m32[widx], 1u << (ln & 31));
        }
        for (int j = tid; j < I_NO; j += 256) {
            int a = 0;
            for (int s = 0; s < SUB_NO; ++s)
                if (Csi[s * I_NO + j] > 0.5f) a = s;
            int ln = j >> 2, cp = j & 3;
            int widx = 320 + (a * 4 + cp) * 2 + (ln >> 5);
            atomicOr(&m32[widx], 1u << (ln & 31));
        }
        __syncthreads();
        for (int k = tid; k < 480; k += 256) masks32[k] = m32[k];
        return;
    }

    for (int it = tid; it < N_BASIS * T_NO; it += 256) {
        int bb = it / T_NO, j = it - bb * T_NO;
        float phi = 1.57079632679489662f * (float)bb;
        float raw = 5.0f * logf((float)j + 1.0f);
        float v = 0.f;
        if (raw >= phi - PI && raw <= phi + PI) v = 0.5f * cosf(raw - phi) + 0.5f;
        cb[it] = v;
    }
    __syncthreads();

    if (b < 20) {
        const int s = b;
        if (tid < T_NO) {
            const int j = tid;
            float tau_e = Tau[s * 2 + 0]; tau_e *= tau_e;
            float tau_i = Tau[s * 2 + 1]; tau_i *= tau_i;
            float de = Del[s * 2 + 0], di = Del[s * 2 + 1];
            float we = Wns[s * 2 + 0]; we *= we;
            float wi = Wns[s * 2 + 1]; wi *= wi;
            float te = fmaxf((float)j - de, 0.f) / tau_e;
            float ti = fmaxf((float)j - di, 0.f) / tau_i;
            float eNs = te * expf(-te) * we;
            float iNs = -ti * expf(-ti) * wi;
            float eS = 0.f, iS = 0.f;
            for (int bb = 0; bb < N_BASIS; ++bb) {
                float w0 = Wsyns[(s * N_BASIS + bb) * 2 + 0];
                float w1 = Wsyns[(s * N_BASIS + bb) * 2 + 1];
                float c = cb[bb * T_NO + j];
                eS += w0 * w0 * c;
                iS -= w1 * w1 * c;
            }
            int it = s * T_NO + j;
            outF[it]         = eNs;
            outF[4000 + it]  = iNs;
            outF[8000 + it]  = eS;
            outF[12000 + it] = iS;
            u32 pN = (u32)f2h(eNs) | ((u32)f2h(iNs) << 16);
            u32 pS = (u32)f2h(eS)  | ((u32)f2h(iS)  << 16);
            ktap[s * T_NO + (199 - j)] = make_uint2(pN, pS);
        }
    } else {
        if (tid < T_NO) {
            const int j = tid;
            float hn = 0.f, hs = 0.f;
            for (int bb = 0; bb < N_BASIS; ++bb) {
                float c = cb[bb * T_NO + j];
                hn += HwNS[bb] * c;
                hs += HwS[bb] * c;
            }
            outF[16000 + j] = hn;
            outF[16200 + j] = hs;
            ktap[20 * T_NO + (199 - j)] = make_uint2((u32)f2h(hn), (u32)f2h(hs));
        }
    }
}

// ============================================================================
// k_spikes (ballot+popcount): lanes = columns (coalesced float4 loads),
// lanes 0..19 hold per-E-subunit masks, 20..39 per-I-subunit masks.
// 16 t per wave, 3125 blocks (12.2 blocks/CU -> 6% tail vs 31% before).
// Writeout packs (e,i) counts as f16 pairs -> one u32 stream per subunit.
// ============================================================================
__global__ __launch_bounds__(256) void k_spikes(
    const float* __restrict__ Se, const float* __restrict__ Si,
    const u64* __restrict__ masks,
    u32* __restrict__ synEI)
{
    __shared__ u16 tile[4][40 * 18];     // per wave [40 rows][16 t], stride 18
    const int tid = threadIdx.x;
    const int wv = tid >> 6, lane = tid & 63;
    const int t0 = (blockIdx.x * 4 + wv) * 16;   // 3125*4*16 = 200000 exact

    u64 me0 = 0, me1 = 0, me2 = 0, me3 = 0, me4 = 0, me5 = 0, me6 = 0, me7 = 0;
    u64 mi0 = 0, mi1 = 0, mi2 = 0, mi3 = 0;
    if (lane < 20) {
        const u64* mp = masks + lane * 8;
        me0 = mp[0]; me1 = mp[1]; me2 = mp[2]; me3 = mp[3];
        me4 = mp[4]; me5 = mp[5]; me6 = mp[6]; me7 = mp[7];
    } else if (lane < 40) {
        const u64* mp = masks + 160 + (lane - 20) * 4;
        mi0 = mp[0]; mi1 = mp[1]; mi2 = mp[2]; mi3 = mp[3];
    }
    u16* tw = tile[wv];

#pragma unroll 2
    for (int tt = 0; tt < 16; ++tt) {
        const int t = t0 + tt;
        const float4* rE = (const float4*)(Se + (size_t)t * E_NO);
        const float4* rI = (const float4*)(Si + (size_t)t * I_NO);
        float4 e0 = rE[lane];                                   // cols 0..255
        float4 e1 = make_float4(0.f, 0.f, 0.f, 0.f);            // cols 256..399
        if (lane < 36) e1 = rE[64 + lane];
        float4 i0 = make_float4(0.f, 0.f, 0.f, 0.f);            // cols 0..99
        if (lane < 25) i0 = rI[lane];
        u64 b0 = __ballot(e0.x != 0.f);
        u64 b1 = __ballot(e0.y != 0.f);
        u64 b2 = __ballot(e0.z != 0.f);
        u64 b3 = __ballot(e0.w != 0.f);
        u64 b4 = __ballot(e1.x != 0.f);
        u64 b5 = __ballot(e1.y != 0.f);
        u64 b6 = __ballot(e1.z != 0.f);
        u64 b7 = __ballot(e1.w != 0.f);
        u64 c0 = __ballot(i0.x != 0.f);
        u64 c1 = __ballot(i0.y != 0.f);
        u64 c2 = __ballot(i0.z != 0.f);
        u64 c3 = __ballot(i0.w != 0.f);
        if (lane < 20) {
            int c = __popcll(b0 & me0) + __popcll(b1 & me1)
                  + __popcll(b2 & me2) + __popcll(b3 & me3)
                  + __popcll(b4 & me4) + __popcll(b5 & me5)
                  + __popcll(b6 & me6) + __popcll(b7 & me7);
            tw[lane * 18 + tt] = (u16)c;
        } else if (lane < 40) {
            int c = __popcll(c0 & mi0) + __popcll(c1 & mi1)
                  + __popcll(c2 & mi2) + __popcll(c3 & mi3);
            tw[lane * 18 + tt] = (u16)c;
        }
    }
    // intra-wave cross-lane LDS visibility (no block barrier needed)
    asm volatile("s_waitcnt lgkmcnt(0)" ::: "memory");

    if (lane < 16) {
#pragma unroll
        for (int s = 0; s < 20; ++s) {
            float fe = (float)tw[s * 18 + lane];
            float fi = (float)tw[(20 + s) * 18 + lane];
            u32 v = (u32)f2h(fe) | ((u32)f2h(fi) << 16);
            synEI[(size_t)s * T_DATA + t0 + lane] = v;
        }
    }
}

// ============================================================================
// k_conv: depthwise conv via v_dot2_f32_f16. blockIdx.y 0..4 = 4 subunits
// each (wave = one subunit over 512 t); 5 = hist-of-Z. Data = interleaved
// (e,i) f16 pairs in LDS; taps = reversed f16 pairs from global at
// wave-uniform (scalar) address. Sliding 16-u32 register window: 2 b128
// LDS reads per 8-tap block. 11.4 KB LDS.
// ============================================================================
#define TT 512
#define WROW 712
__global__ __launch_bounds__(256) void k_conv(
    const u32* __restrict__ synEI, const float* __restrict__ Z,
    const uint2* __restrict__ ktap,
    u16* __restrict__ synNSb, u16* __restrict__ synSb,
    float2* __restrict__ hfilt)
{
    __shared__ __align__(16) u32 wEI[4 * WROW];
    const int tid = threadIdx.x;
    const int t0 = blockIdx.x * TT;
    const int g  = blockIdx.y;
    const int W0 = t0 - 200;

    if (g < 5) {
        for (int q = tid; q < 4 * 178; q += 256) {
            int row = q / 178, c = q - row * 178;
            int s = g * 4 + row;
            const u32* src = synEI + (size_t)s * T_DATA;
            u32* dst = wEI + row * WROW + c * 4;
            int gg = W0 + c * 4;
            if (gg >= 0 && gg + 4 <= T_DATA) {
                *(uint4*)dst = *(const uint4*)(src + gg);
            } else {
#pragma unroll
                for (int e = 0; e < 4; ++e) {
                    int t = gg + e;
                    dst[e] = (t >= 0 && t < T_DATA) ? src[t] : 0u;
                }
            }
        }
    } else {
        for (int q = tid; q < 3 * 178; q += 256)
            ((uint4*)(wEI + WROW))[q] = make_uint4(0, 0, 0, 0);
        for (int c = tid; c < 178; c += 256) {
            int gg = W0 + c * 4;
            u32 o[4];
#pragma unroll
            for (int e = 0; e < 4; ++e) {
                int t = gg + e;
                float z = (t >= 0 && t < T_DATA) ? Z[t] : 0.f;
                o[e] = (u32)f2h(z);          // low = Z, high = 0
            }
            *(uint4*)(wEI + c * 4) = make_uint4(o[0], o[1], o[2], o[3]);
        }
    }
    __syncthreads();

    const int wv = tid >> 6;
    const int slot = tid & 63;
    const int bT = slot * 8;
    const u32* row = wEI + wv * WROW;
    const int su = (g < 5) ? (g * 4 + wv) : 20;
    const uint2* kt = ktap + (size_t)__builtin_amdgcn_readfirstlane(su) * T_NO;

    float aN[8], aS[8];
#pragma unroll
    for (int m = 0; m < 8; ++m) { aN[m] = 0.f; aS[m] = 0.f; }

    // register window x[0..15] = L[bT+jj .. bT+jj+16)
    u32 x[16];
    {
        uint4 wA = *(const uint4*)(row + bT);
        uint4 wB = *(const uint4*)(row + bT + 4);
        uint4 wC = *(const uint4*)(row + bT + 8);
        uint4 wD = *(const uint4*)(row + bT + 12);
        x[0]=wA.x; x[1]=wA.y; x[2]=wA.z; x[3]=wA.w;
        x[4]=wB.x; x[5]=wB.y; x[6]=wB.z; x[7]=wB.w;
        x[8]=wC.x; x[9]=wC.y; x[10]=wC.z; x[11]=wC.w;
        x[12]=wD.x; x[13]=wD.y; x[14]=wD.z; x[15]=wD.w;
    }

#pragma unroll 1
    for (int jj = 0; jj <= 192; jj += 8) {
        uint2 kp[8];
#pragma unroll
        for (int k = 0; k < 8; ++k) kp[k] = kt[jj + k];
#pragma unroll
        for (int k = 0; k < 8; ++k) {
#pragma unroll
            for (int m = 0; m < 8; ++m) {
                aN[m] = dot2(x[m + 1 + k], kp[k].x, aN[m]);
                aS[m] = dot2(x[m + 1 + k], kp[k].y, aS[m]);
            }
        }
        if (jj < 192) {
#pragma unroll
            for (int i = 0; i < 8; ++i) x[i] = x[i + 8];
            uint4 nA = *(const uint4*)(row + bT + jj + 16);
            uint4 nB = *(const uint4*)(row + bT + jj + 20);
            x[8]=nA.x; x[9]=nA.y; x[10]=nA.z; x[11]=nA.w;
            x[12]=nB.x; x[13]=nB.y; x[14]=nB.z; x[15]=nB.w;
        }
    }

    if (g < 5) {
        const int s = g * 4 + wv;
        const int t = t0 + bT;
        u32 w0 = (u32)f2h(aN[0]) | ((u32)f2h(aN[1]) << 16);
        u32 w1 = (u32)f2h(aN[2]) | ((u32)f2h(aN[3]) << 16);
        u32 w2 = (u32)f2h(aN[4]) | ((u32)f2h(aN[5]) << 16);
        u32 w3 = (u32)f2h(aN[6]) | ((u32)f2h(aN[7]) << 16);
        u32 v0 = (u32)f2h(aS[0]) | ((u32)f2h(aS[1]) << 16);
        u32 v1 = (u32)f2h(aS[2]) | ((u32)f2h(aS[3]) << 16);
        u32 v2 = (u32)f2h(aS[4]) | ((u32)f2h(aS[5]) << 16);
        u32 v3 = (u32)f2h(aS[6]) | ((u32)f2h(aS[7]) << 16);
        if (t + 8 <= T_DATA) {
            *(uint4*)(synNSb + (size_t)s * T_DATA + t) = make_uint4(w0, w1, w2, w3);
            *(uint4*)(synSb  + (size_t)s * T_DATA + t) = make_uint4(v0, v1, v2, v3);
        } else if (t < T_DATA) {
            for (int m = 0; m < 8 && t + m < T_DATA; ++m) {
                synNSb[(size_t)s * T_DATA + t + m] = f2h(aN[m]);
                synSb[(size_t)s * T_DATA + t + m] = f2h(aS[m]);
            }
        }
    } else if (wv == 0) {
#pragma unroll
        for (int m = 0; m < 8; ++m) {
            int tt = t0 + bT + m + 1;
            if (tt < T_DATA) hfilt[tt] = make_float2(aN[m], aS[m]);
        }
        if (blockIdx.x == 0 && tid == 0) hfilt[0] = make_float2(0.f, 0.f);
    }
}

// ============================================================================
// k_tree: tree recursion + f32 outputs (hist precomputed). f16 inputs.
// ============================================================================
#define CT 256
__global__ __launch_bounds__(256) void k_tree(
    const u16* __restrict__ synNSb, const u16* __restrict__ synSb,
    const float2* __restrict__ hfilt,
    const int* __restrict__ Cden,
    const float* __restrict__ WsubNS, const float* __restrict__ WsubS,
    const float* __restrict__ Vo, const float* __restrict__ ThNS,
    const float* __restrict__ ThS,
    float* __restrict__ outV, float* __restrict__ outZ)
{
    __shared__ __align__(16) u16 lNS[SUB_NO * CT];
    __shared__ __align__(16) u16 lS[SUB_NO * CT];
    __shared__ float AS[SUB_NO][SUB_NO], AN[SUB_NO][SUB_NO];
    __shared__ float ths[SUB_NO], thn[SUB_NO];
    __shared__ float wn20s, vos;
    const int tid = threadIdx.x;
    const int t0 = blockIdx.x * CT;

    for (int q = tid; q < 1280; q += 256) {
        int arr = (q >= 640) ? 1 : 0;
        int qq = q - arr * 640;
        int row = qq >> 5, c = qq & 31;
        const u16* src = (arr ? synSb : synNSb) + (size_t)row * T_DATA;
        u16* dst = (arr ? lS : lNS) + row * CT + c * 8;
        int gg = t0 + c * 8;
        if (gg + 8 <= T_DATA) {
            *(uint4*)dst = *(const uint4*)(src + gg);
        } else {
            for (int e = 0; e < 8; ++e) {
                int t = gg + e;
                dst[e] = (t < T_DATA) ? src[t] : (u16)0;
            }
        }
    }
    for (int k = tid; k < SUB_NO * SUB_NO; k += 256) {
        int idx = k / SUB_NO, c = k - idx * SUB_NO;
        float m = (float)Cden[k];
        float wsv = WsubS[c];
        float wnv = WsubNS[c];
        AS[idx][c] = m * wsv * wsv;
        AN[idx][c] = m * wnv * wnv;
    }
    if (tid < SUB_NO) { ths[tid] = ThS[tid]; thn[tid] = ThNS[tid]; }
    if (tid == 0) {
        float w = WsubNS[0];
        wn20s = w * w;
        vos = Vo[0];
    }
    __syncthreads();

    const int t = t0 + tid;
    float2 hf = make_float2(0.f, 0.f);
    if (t < T_DATA) hf = hfilt[t];

    float vs[SUB_NO], vn[SUB_NO];
#pragma unroll
    for (int c = 0; c < SUB_NO; ++c) { vs[c] = 0.f; vn[c] = 0.f; }
#pragma unroll
    for (int idx = SUB_NO - 1; idx >= 1; --idx) {
        float cs = 0.f, cn = 0.f;
#pragma unroll
        for (int c = 0; c < SUB_NO; ++c) {
            cs = fmaf(AS[idx][c], vs[c], cs);
            cn = fmaf(AN[idx][c], vn[c], cn);
        }
        float synS_v = h2f(lS[idx * CT + tid]);
        float synN_v = h2f(lNS[idx * CT + tid]);
        vs[idx] = fast_tanh(synS_v + cs + ths[idx]);
        vn[idx] = fast_tanh(synN_v + cn + thn[idx]);
    }
    float cs0 = 0.f, cn0 = 0.f;
#pragma unroll
    for (int c = 0; c < SUB_NO; ++c) {
        cs0 = fmaf(AS[0][c], vs[c], cs0);
        cn0 = fmaf(AN[0][c], vn[c], cn0);
    }
    float s0  = fast_sigmoid(hf.y + h2f(lS[tid]) + cs0 + ths[0]);
    float ns0 = fast_tanh(hf.x + h2f(lNS[tid]) + cn0 + thn[0]);

    if (t < T_DATA) {
        outV[t] = ns0 * wn20s + vos;
        outZ[t] = s0;
    }
}

// ============================================================================
extern "C" void kernel_launch(void* const* d_in, const int* in_sizes, int n_in,
                              void* d_out, int out_size, void* d_ws, size_t ws_size,
                              hipStream_t stream)
{
    const float* Se    = (const float*)d_in[0];
    const float* Si    = (const float*)d_in[1];
    const float* Z     = (const float*)d_in[2];
    const int*   Cden  = (const int*)d_in[3];
    const float* Cse   = (const float*)d_in[4];
    const float* Csi   = (const float*)d_in[5];
    const float* Wns   = (const float*)d_in[6];
    const float* Tau   = (const float*)d_in[7];
    const float* Del   = (const float*)d_in[8];
    const float* Wsyns = (const float*)d_in[9];
    const float* WsubNS= (const float*)d_in[10];
    const float* WsubS = (const float*)d_in[11];
    const float* Vo    = (const float*)d_in[12];
    const float* ThNS  = (const float*)d_in[13];
    const float* ThS   = (const float*)d_in[14];
    const float* HwS   = (const float*)d_in[15];
    const float* HwNS  = (const float*)d_in[16];

    char* ws = (char*)d_ws;
    uint2*  ktap  = (uint2*)(ws + WS_KT);
    u64*    masks = (u64*)(ws + WS_MASKS);
    u32*    synEI = (u32*)(ws + WS_SYNEI);
    u16*    synNSb= (u16*)(ws + WS_SNS);
    u16*    synSb = (u16*)(ws + WS_SS);
    float2* hfilt = (float2*)(ws + WS_HF);

    float* outV = (float*)d_out;
    float* outZ = outV + T_DATA;
    float* outF = outV + 2 * T_DATA;

    k_setup<<<22, 256, 0, stream>>>(Wns, Tau, Del, Wsyns, HwS, HwNS, Cse, Csi,
                                    ktap, (u32*)masks, outF);
    // 12500 waves x 16 t, 4 waves/block -> 3125 blocks (12.2/CU, ~6% tail)
    k_spikes<<<3125, 256, 0, stream>>>(Se, Si, masks, synEI);
    dim3 gc((T_DATA + TT - 1) / TT, 6);
    k_conv<<<gc, 256, 0, stream>>>(synEI, Z, ktap, synNSb, synSb, hfilt);
    k_tree<<<(T_DATA + CT - 1) / CT, 256, 0, stream>>>(
        synNSb, synSb, hfilt, Cden, WsubNS, WsubS, Vo, ThNS, ThS,
        outV, outZ);
}